// Round 10
// baseline (1165.796 us; speedup 1.0000x reference)
//
#include <hip/hip_runtime.h>
#include <math.h>

#define NN 20000   // nodes
#define NE 100000  // edges per edge set
#define DD 128     // hidden
#define FF 16      // node features
#define NL 12      // layers
#define NG 64      // graphs
#define NBLK 79    // ceil(NN/256)
#define NTILE 313  // ceil(NN/64)
#define NCHUNK 1563   // ceil(NE/64)
#define NMSGBLK 782   // ceil(NCHUNK/2)

typedef unsigned short u16;
typedef short short8 __attribute__((ext_vector_type(8)));
typedef float f32x4 __attribute__((ext_vector_type(4)));

__device__ __forceinline__ float silu_f(float x) { return x / (1.0f + __expf(-x)); }

__device__ __forceinline__ u16 f2b(float f) {
    union { float f; unsigned int u; } v; v.f = f;
    unsigned int r = v.u + 0x7fffu + ((v.u >> 16) & 1u);
    return (u16)(r >> 16);
}
__device__ __forceinline__ float b2f(u16 b) {
    union { unsigned int u; float f; } v; v.u = ((unsigned int)b) << 16;
    return v.f;
}

// ---- merged weight prep: all 4 tensors, fp32 -> bf16 transposed ----
__device__ __forceinline__ void wprep_one(const float* src, u16* dst, int idx,
                                          int Ksrc, int Kdst) {
    int k = idx % Kdst;
    int c = (idx / Kdst) & 127;
    int l = idx / (Kdst * 128);
    dst[idx] = f2b(src[((size_t)l * Ksrc + k) * 128 + c]);
}
__global__ void wprep_all_kernel(const float* __restrict__ mW1, const float* __restrict__ mW2,
                                 const float* __restrict__ uW1, const float* __restrict__ uW2,
                                 u16* __restrict__ dmW1, u16* __restrict__ dmW2,
                                 u16* __restrict__ duW1, u16* __restrict__ duW2) {
    const int S1 = NL * 128 * 256, S2 = NL * 128 * 128;
    int gid = blockIdx.x * 256 + threadIdx.x;
    if (gid < S1) { wprep_one(mW1, dmW1, gid, 257, 256); return; }
    gid -= S1;
    if (gid < S2) { wprep_one(mW2, dmW2, gid, 128, 128); return; }
    gid -= S2;
    if (gid < S1) { wprep_one(uW1, duW1, gid, 256, 256); return; }
    gid -= S1;
    if (gid < S2) { wprep_one(uW2, duW2, gid, 128, 128); return; }
}

// ---- embedding ----
__global__ void embed_kernel(const float* __restrict__ x, const float* __restrict__ W,
                             const float* __restrict__ b, float* __restrict__ h,
                             u16* __restrict__ hb) {
    int gid = blockIdx.x * 256 + threadIdx.x;
    if (gid >= NN * DD) return;
    int n = gid >> 7, c = gid & 127;
    float s = b[c];
    const float* xr = x + n * FF;
#pragma unroll
    for (int k = 0; k < FF; ++k) s += xr[k] * W[k * DD + c];
    h[gid] = s;
    hb[gid] = f2b(s);
}

// ================== CSR build (once per call, all 4 edge sets) ==================
__global__ void hist_kernel(const int* __restrict__ e0, const int* __restrict__ e1,
                            const int* __restrict__ e2, const int* __restrict__ e3,
                            int* __restrict__ cnt) {
    int g = blockIdx.x * 256 + threadIdx.x;
    if (g >= 4 * NE) return;
    int set = g / NE, e = g - set * NE;
    const int* ei = (set == 0) ? e0 : (set == 1) ? e1 : (set == 2) ? e2 : e3;
    atomicAdd(&cnt[set * NN + ei[NE + e]], 1);
}

__global__ __launch_bounds__(256)
void scanA_kernel(const int* __restrict__ cnt, int* __restrict__ rowptr,
                  int* __restrict__ blksum) {
    int set = blockIdx.x / NBLK, blk = blockIdx.x % NBLK;
    int t = threadIdx.x, idx = blk * 256 + t;
    int v = (idx < NN) ? cnt[set * NN + idx] : 0;
    __shared__ int part[256];
    part[t] = v;
    __syncthreads();
    for (int off = 1; off < 256; off <<= 1) {
        int nv = (t >= off) ? part[t - off] : 0;
        __syncthreads();
        part[t] += nv;
        __syncthreads();
    }
    if (idx < NN) rowptr[set * NN + idx] = part[t] - v;
    if (t == 255) blksum[set * NBLK + blk] = part[255];
}

__global__ __launch_bounds__(128)
void scanB_kernel(const int* __restrict__ blksum, int* __restrict__ blkoff) {
    int set = blockIdx.x, t = threadIdx.x;
    int v = (t < NBLK) ? blksum[set * NBLK + t] : 0;
    __shared__ int part[128];
    part[t] = v;
    __syncthreads();
    for (int off = 1; off < 128; off <<= 1) {
        int nv = (t >= off) ? part[t - off] : 0;
        __syncthreads();
        part[t] += nv;
        __syncthreads();
    }
    if (t < NBLK) blkoff[set * NBLK + t] = part[t] - v;
}

__global__ __launch_bounds__(256)
void scanC_kernel(const int* __restrict__ blkoff, int* __restrict__ rowptr,
                  int* __restrict__ cursor) {
    int set = blockIdx.x / NBLK, blk = blockIdx.x % NBLK;
    int t = threadIdx.x, idx = blk * 256 + t;
    if (idx >= NN) return;
    int r = rowptr[set * NN + idx] + blkoff[set * NBLK + blk];
    rowptr[set * NN + idx] = r;
    cursor[set * NN + idx] = r;
}

__global__ void scatter_kernel(const int* __restrict__ e0, const int* __restrict__ e1,
                               const int* __restrict__ e2, const int* __restrict__ e3,
                               const float* __restrict__ pos,
                               int* __restrict__ cursor,
                               int* __restrict__ src_s, int* __restrict__ dst_s,
                               float* __restrict__ dist_s) {
    int g = blockIdx.x * 256 + threadIdx.x;
    if (g >= 4 * NE) return;
    int set = g / NE, e = g - set * NE;
    const int* ei = (set == 0) ? e0 : (set == 1) ? e1 : (set == 2) ? e2 : e3;
    int s = ei[e], d = ei[NE + e];
    int p = atomicAdd(&cursor[set * NN + d], 1);
    float dx = pos[d * 3 + 0] - pos[s * 3 + 0];
    float dy = pos[d * 3 + 1] - pos[s * 3 + 1];
    float dz = pos[d * 3 + 2] - pos[s * 3 + 2];
    src_s[(size_t)set * NE + p] = s;
    dst_s[(size_t)set * NE + p] = d;
    dist_s[(size_t)set * NE + p] = sqrtf(dx * dx + dy * dy + dz * dz);
}

// ===== initial pre (layer 0 only): Pd = h@W1[0:128]+b1 ; Ps = h@W1[128:256] =====
__global__ __launch_bounds__(256, 4)
void pre_kernel(const u16* __restrict__ hb, const u16* __restrict__ W1T,
                const float* __restrict__ b1,
                u16* __restrict__ Pd, u16* __restrict__ Ps) {
    __shared__ __align__(16) u16 As[64 * 40];
    __shared__ __align__(16) u16 Ws[128 * 40];

    const int tid = threadIdx.x;
    const int lane = tid & 63;
    const int w = tid >> 6;
    const int r0 = w * 16;
    const int arow = lane & 15;
    const int kg = lane >> 4;
    const int n0 = blockIdx.x * 64;
    const int part = blockIdx.y;
    u16* outp = part ? Ps : Pd;

    f32x4 acc[8];
#pragma unroll
    for (int t = 0; t < 8; ++t) acc[t] = (f32x4)0.f;

    const int s_row = tid >> 2, s_k8 = (tid & 3) * 8;
    const int w_col = tid >> 1, w_k16 = (tid & 1) * 16;

    for (int kc = 0; kc < 4; ++kc) {
        const int kb = kc * 32;
        {
            int n = n0 + s_row;
            int nn = (n < NN) ? n : 0;
            *(short8*)&As[s_row * 40 + s_k8] =
                *(const short8*)&hb[(size_t)nn * DD + kb + s_k8];
            const u16* wsrc = &W1T[(size_t)w_col * 256 + part * 128 + kb + w_k16];
            *(short8*)&Ws[w_col * 40 + w_k16]     = *(const short8*)&wsrc[0];
            *(short8*)&Ws[w_col * 40 + w_k16 + 8] = *(const short8*)&wsrc[8];
        }
        __syncthreads();
        short8 a = *(const short8*)&As[(r0 + arow) * 40 + kg * 8];
#pragma unroll
        for (int t = 0; t < 8; ++t) {
            short8 b = *(const short8*)&Ws[(t * 16 + arow) * 40 + kg * 8];
            acc[t] = __builtin_amdgcn_mfma_f32_16x16x32_bf16(a, b, acc[t], 0, 0, 0);
        }
        __syncthreads();
    }

#pragma unroll
    for (int r = 0; r < 4; ++r) {
        int n = n0 + r0 + kg * 4 + r;
        if (n < NN) {
            u16* op = &outp[(size_t)n * DD];
#pragma unroll
            for (int t = 0; t < 8; ++t) {
                int col = t * 16 + arow;
                float v = acc[t][r] + (part == 0 ? b1[col] : 0.f);
                op[col] = f2b(v);
            }
        }
    }
}

// =======================================================================
// msg: edge MLP, phase A in MFMA A-fragment registers; 2 chunks per block
// (W2 staged once, LN2 params hoisted); dlS double-buffered
// =======================================================================
__global__ __launch_bounds__(256, 3)
void msg_kernel(const u16* __restrict__ Pd, const u16* __restrict__ Ps,
                const int* __restrict__ src_s, const int* __restrict__ dst_s,
                const float* __restrict__ dist_s,
                const float* __restrict__ wd,
                const float* __restrict__ g1, const float* __restrict__ be1,
                const u16* __restrict__ W2T,
                const float* __restrict__ b2, const float* __restrict__ g2,
                const float* __restrict__ be2,
                float* __restrict__ agg) {
    __shared__ __align__(16) u16 Ws[128 * 136];  // full W2 [c][k], stride-136 pad
    __shared__ __align__(16) u16 Mt[64 * 128];
    __shared__ int dlS[2][64];                   // double-buffered per chunk

    const int tid = threadIdx.x;
    const int lane = tid & 63;
    const int w = tid >> 6;
    const int r0 = w * 16;
    const int arow = lane & 15;
    const int kg = lane >> 4;

    // stage full W2 once per block
#pragma unroll
    for (int q = 0; q < 8; ++q) {
        int idx = q * 256 + tid;
        int c = idx >> 4, k8 = (idx & 15) * 8;
        *(short8*)&Ws[c * 136 + k8] = *(const short8*)&W2T[(size_t)c * 128 + k8];
    }

    // hoist LN2 params (depend only on arow)
    float gg[8], ee[8], bb[8];
#pragma unroll
    for (int t = 0; t < 8; ++t) {
        int col = t * 16 + arow;
        bb[t] = b2[col]; gg[t] = g2[col]; ee[t] = be2[col];
    }

    const int erow = r0 + arow;

    for (int c = 0; c < 2; ++c) {
        const int chunk = blockIdx.x * 2 + c;
        if (chunk >= NCHUNK) break;
        const int e0 = chunk * 64;
        int* dl = dlS[c];

        // ---- phase A in registers (A-fragment layout) ----
        const int slot = e0 + erow;
        const bool valid = slot < NE;
        int sn = 0, dn = 0; float dist = 0.f;
        if (valid) { sn = src_s[slot]; dn = dst_s[slot]; dist = dist_s[slot]; }
        if (kg == 0) dl[erow] = valid ? dn : -1;

        float vals[4][8];
        float s1 = 0.f, s2 = 0.f;
#pragma unroll
        for (int kc = 0; kc < 4; ++kc) {
            int kb = kc * 32 + kg * 8;
            short8 pd = *(const short8*)&Pd[(size_t)dn * DD + kb];
            short8 ps = *(const short8*)&Ps[(size_t)sn * DD + kb];
            float4 w0 = *(const float4*)&wd[kb];
            float4 w1 = *(const float4*)&wd[kb + 4];
            float wv[8] = {w0.x, w0.y, w0.z, w0.w, w1.x, w1.y, w1.z, w1.w};
#pragma unroll
            for (int j = 0; j < 8; ++j) {
                float val = b2f((u16)pd[j]) + b2f((u16)ps[j]) + dist * wv[j];
                vals[kc][j] = val;
                s1 += val; s2 += val * val;
            }
        }
        s1 += __shfl_xor(s1, 16); s2 += __shfl_xor(s2, 16);
        s1 += __shfl_xor(s1, 32); s2 += __shfl_xor(s2, 32);
        float mu = s1 * (1.f / 128.f);
        float var = s2 * (1.f / 128.f) - mu * mu;
        float rs = rsqrtf(var + 1e-5f);

        short8 afrag[4];
#pragma unroll
        for (int kc = 0; kc < 4; ++kc) {
            int kb = kc * 32 + kg * 8;
            float4 ga = *(const float4*)&g1[kb];
            float4 gb = *(const float4*)&g1[kb + 4];
            float4 ea = *(const float4*)&be1[kb];
            float4 eb = *(const float4*)&be1[kb + 4];
            float gv[8] = {ga.x, ga.y, ga.z, ga.w, gb.x, gb.y, gb.z, gb.w};
            float ev[8] = {ea.x, ea.y, ea.z, ea.w, eb.x, eb.y, eb.z, eb.w};
            u16 tmp[8];
#pragma unroll
            for (int j = 0; j < 8; ++j) {
                float val = (vals[kc][j] - mu) * rs * gv[j] + ev[j];
                tmp[j] = f2b(silu_f(val));
            }
            afrag[kc] = *(const short8*)tmp;
        }

        __syncthreads();  // publishes Ws (chunk 0) + dl; separates prev reduce from Mt rewrite

        // ---- GEMM2: A from registers ----
        f32x4 acc[8];
#pragma unroll
        for (int t = 0; t < 8; ++t) acc[t] = (f32x4)0.f;
#pragma unroll
        for (int kc = 0; kc < 4; ++kc) {
#pragma unroll
            for (int t = 0; t < 8; ++t) {
                short8 b = *(const short8*)&Ws[(t * 16 + arow) * 136 + kc * 32 + kg * 8];
                acc[t] = __builtin_amdgcn_mfma_f32_16x16x32_bf16(afrag[kc], b, acc[t], 0, 0, 0);
            }
        }

        // ---- LN2 + SiLU -> Mt ----
#pragma unroll
        for (int r = 0; r < 4; ++r) {
            int row = r0 + kg * 4 + r;
            float t1 = 0.f, t2 = 0.f;
#pragma unroll
            for (int t = 0; t < 8; ++t) {
                float val = acc[t][r] + bb[t]; acc[t][r] = val; t1 += val; t2 += val * val;
            }
#pragma unroll
            for (int m = 1; m < 16; m <<= 1) { t1 += __shfl_xor(t1, m); t2 += __shfl_xor(t2, m); }
            float mu2 = t1 * (1.f / 128.f);
            float var2 = t2 * (1.f / 128.f) - mu2 * mu2;
            float rs2 = rsqrtf(var2 + 1e-5f);
#pragma unroll
            for (int t = 0; t < 8; ++t) {
                float val = (acc[t][r] - mu2) * rs2 * gg[t] + ee[t];
                Mt[row * 128 + t * 16 + arow] = f2b(silu_f(val));
            }
        }
        __syncthreads();  // publishes Mt

        // ---- segmented reduce -> agg ----
        {
            int col = tid & 127;
            int half = tid >> 7;
            int rb = half * 32;
            int prev_dst = (rb == 0) ? ((e0 > 0) ? dst_s[e0 - 1] : -2) : dl[31];
            int next_dst = (rb == 0) ? dl[32]
                                     : ((e0 + 64 < NE) ? dst_s[e0 + 64] : -2);
            float run = 0.f;
            int cur = -1;
            bool cur_shared = false;
            for (int r = rb; r < rb + 32; ++r) {
                int d = dl[r];
                if (d != cur) {
                    if (cur >= 0) {
                        float* ap = &agg[(size_t)cur * 128 + col];
                        if (cur_shared) atomicAdd(ap, run); else *ap = run;
                    }
                    cur = d; run = 0.f;
                    cur_shared = (r == rb) && (prev_dst == d);
                }
                if (d >= 0) run += b2f(Mt[r * 128 + col]);
            }
            if (cur >= 0) {
                bool shared_end = (next_dst == cur);
                float* ap = &agg[(size_t)cur * 128 + col];
                if (cur_shared || shared_end) atomicAdd(ap, run); else *ap = run;
            }
        }
    }
}

// =======================================================================
// upd: node MLP + residual + next-layer Pd/Ps
// A-fragments direct from global; ping-pong Ws (1 barrier/chunk)
// =======================================================================
__global__ __launch_bounds__(256, 4)
void upd_kernel(float* __restrict__ h, u16* __restrict__ hb,
                float* __restrict__ agg,
                const u16* __restrict__ W1T,
                const float* __restrict__ b1, const float* __restrict__ g1,
                const float* __restrict__ be1,
                const u16* __restrict__ W2T,
                const float* __restrict__ b2, const float* __restrict__ g2,
                const float* __restrict__ be2,
                const u16* __restrict__ nW1T, const float* __restrict__ nb1,
                u16* __restrict__ Pd_n, u16* __restrict__ Ps_n,
                int donext) {
    __shared__ __align__(16) u16 Ws[2][128 * 40];
    __shared__ __align__(16) u16 Mt[64 * 136];
    u16* newh = Mt;

    const int tid = threadIdx.x;
    const int lane = tid & 63;
    const int w = tid >> 6;
    const int r0 = w * 16;
    const int arow = lane & 15;
    const int kg = lane >> 4;
    const int n0 = blockIdx.x * 64;

    const int w_col = tid >> 1, w_k16 = (tid & 1) * 16;
    const int myn = n0 + r0 + arow;
    const int nclamp = (myn < NN) ? myn : 0;

    f32x4 acc[8];
#pragma unroll
    for (int t = 0; t < 8; ++t) acc[t] = (f32x4)0.f;

    for (int kc = 0; kc < 8; ++kc) {
        const int kb = kc * 32;
        u16* wbuf = Ws[kc & 1];
        {
            const u16* wsrc = &W1T[(size_t)w_col * 256 + kb + w_k16];
            *(short8*)&wbuf[w_col * 40 + w_k16]     = *(const short8*)&wsrc[0];
            *(short8*)&wbuf[w_col * 40 + w_k16 + 8] = *(const short8*)&wsrc[8];
        }
        short8 a;
        if (kc < 4) {
            a = *(const short8*)&hb[(size_t)nclamp * DD + kb + kg * 8];
        } else {
            const float* ap = &agg[(size_t)nclamp * DD + (kb - DD) + kg * 8];
            float4 f0 = *(const float4*)ap;
            float4 f1 = *(const float4*)(ap + 4);
            u16 tmp[8];
            tmp[0] = f2b(f0.x); tmp[1] = f2b(f0.y); tmp[2] = f2b(f0.z); tmp[3] = f2b(f0.w);
            tmp[4] = f2b(f1.x); tmp[5] = f2b(f1.y); tmp[6] = f2b(f1.z); tmp[7] = f2b(f1.w);
            a = *(const short8*)tmp;
        }
        __syncthreads();
#pragma unroll
        for (int t = 0; t < 8; ++t) {
            short8 b = *(const short8*)&wbuf[(t * 16 + arow) * 40 + kg * 8];
            acc[t] = __builtin_amdgcn_mfma_f32_16x16x32_bf16(a, b, acc[t], 0, 0, 0);
        }
    }

    for (int i = tid; i < 64 * 128; i += 256) {
        int n = n0 + (i >> 7);
        if (n < NN) agg[(size_t)n * DD + (i & 127)] = 0.f;
    }

    {
        float gg[8], ee[8], bb[8];
#pragma unroll
        for (int t = 0; t < 8; ++t) {
            int col = t * 16 + arow;
            bb[t] = b1[col]; gg[t] = g1[col]; ee[t] = be1[col];
        }
#pragma unroll
        for (int r = 0; r < 4; ++r) {
            float s1 = 0.f, s2 = 0.f;
#pragma unroll
            for (int t = 0; t < 8; ++t) {
                float v = acc[t][r] + bb[t]; acc[t][r] = v; s1 += v; s2 += v * v;
            }
#pragma unroll
            for (int m = 1; m < 16; m <<= 1) { s1 += __shfl_xor(s1, m); s2 += __shfl_xor(s2, m); }
            float mu = s1 * (1.f / 128.f);
            float var = s2 * (1.f / 128.f) - mu * mu;
            float rs = rsqrtf(var + 1e-5f);
            int row = r0 + kg * 4 + r;
#pragma unroll
            for (int t = 0; t < 8; ++t) {
                float v = (acc[t][r] - mu) * rs * gg[t] + ee[t];
                Mt[row * 136 + t * 16 + arow] = f2b(silu_f(v));
            }
        }
    }

#pragma unroll
    for (int t = 0; t < 8; ++t) acc[t] = (f32x4)0.f;
    for (int kc = 0; kc < 4; ++kc) {
        const int kb = kc * 32;
        u16* wbuf = Ws[kc & 1];
        {
            const u16* wsrc = &W2T[(size_t)w_col * 128 + kb + w_k16];
            *(short8*)&wbuf[w_col * 40 + w_k16]     = *(const short8*)&wsrc[0];
            *(short8*)&wbuf[w_col * 40 + w_k16 + 8] = *(const short8*)&wsrc[8];
        }
        __syncthreads();
        short8 a = *(const short8*)&Mt[(r0 + arow) * 136 + kb + kg * 8];
#pragma unroll
        for (int t = 0; t < 8; ++t) {
            short8 b = *(const short8*)&wbuf[(t * 16 + arow) * 40 + kg * 8];
            acc[t] = __builtin_amdgcn_mfma_f32_16x16x32_bf16(a, b, acc[t], 0, 0, 0);
        }
    }

    {
        float gg[8], ee[8], bb[8];
#pragma unroll
        for (int t = 0; t < 8; ++t) {
            int col = t * 16 + arow;
            bb[t] = b2[col]; gg[t] = g2[col]; ee[t] = be2[col];
        }
#pragma unroll
        for (int r = 0; r < 4; ++r) {
            int row = r0 + kg * 4 + r;
            float s1 = 0.f, s2 = 0.f;
#pragma unroll
            for (int t = 0; t < 8; ++t) {
                float v = acc[t][r] + bb[t]; acc[t][r] = v; s1 += v; s2 += v * v;
            }
#pragma unroll
            for (int m = 1; m < 16; m <<= 1) { s1 += __shfl_xor(s1, m); s2 += __shfl_xor(s2, m); }
            float mu = s1 * (1.f / 128.f);
            float var = s2 * (1.f / 128.f) - mu * mu;
            float rs = rsqrtf(var + 1e-5f);
            int n = n0 + row;
            if (n < NN) {
                float* hp = &h[(size_t)n * DD];
                u16* hbp = &hb[(size_t)n * DD];
#pragma unroll
                for (int t = 0; t < 8; ++t) {
                    int col = t * 16 + arow;
                    float v = (acc[t][r] - mu) * rs * gg[t] + ee[t];
                    float nh = hp[col] + silu_f(v);
                    hp[col] = nh;
                    u16 nb = f2b(nh);
                    hbp[col] = nb;
                    newh[row * 136 + col] = nb;
                }
            } else {
#pragma unroll
                for (int t = 0; t < 8; ++t) newh[row * 136 + t * 16 + arow] = 0;
            }
        }
    }

    if (donext) {
        for (int part = 0; part < 2; ++part) {
#pragma unroll
            for (int t = 0; t < 8; ++t) acc[t] = (f32x4)0.f;
            for (int kc = 0; kc < 4; ++kc) {
                const int kb = kc * 32;
                u16* wbuf = Ws[kc & 1];
                {
                    const u16* wsrc = &nW1T[(size_t)w_col * 256 + part * 128 + kb + w_k16];
                    *(short8*)&wbuf[w_col * 40 + w_k16]     = *(const short8*)&wsrc[0];
                    *(short8*)&wbuf[w_col * 40 + w_k16 + 8] = *(const short8*)&wsrc[8];
                }
                __syncthreads();
                short8 a = *(const short8*)&newh[(r0 + arow) * 136 + kb + kg * 8];
#pragma unroll
                for (int t = 0; t < 8; ++t) {
                    short8 b = *(const short8*)&wbuf[(t * 16 + arow) * 40 + kg * 8];
                    acc[t] = __builtin_amdgcn_mfma_f32_16x16x32_bf16(a, b, acc[t], 0, 0, 0);
                }
            }
            u16* outp = part ? Ps_n : Pd_n;
#pragma unroll
            for (int r = 0; r < 4; ++r) {
                int row = r0 + kg * 4 + r;
                int n = n0 + row;
                if (n < NN) {
                    u16* op = &outp[(size_t)n * DD];
#pragma unroll
                    for (int t = 0; t < 8; ++t) {
                        int col = t * 16 + arow;
                        float v = acc[t][r] + (part == 0 ? nb1[col] : 0.f);
                        op[col] = f2b(v);
                    }
                }
            }
            if (part == 0) __syncthreads();
        }
    }
}

// ---------------- global add pool ----------------
__global__ void pool_kernel(const float* __restrict__ h, const int* __restrict__ batch,
                            float* __restrict__ pooled) {
    int gid = blockIdx.x * 256 + threadIdx.x;
    if (gid >= NN * DD) return;
    int n = gid >> 7, c = gid & 127;
    atomicAdd(&pooled[batch[n] * DD + c], h[gid]);
}

// ---------------- prediction head ----------------
__global__ __launch_bounds__(128)
void pred_kernel(const float* __restrict__ pooled,
                 const float* __restrict__ W1, const float* __restrict__ b1,
                 const float* __restrict__ W2, const float* __restrict__ b2,
                 float* __restrict__ out) {
    __shared__ float prow[128];
    __shared__ float wsum[2];
    int g = blockIdx.x, c = threadIdx.x;
    prow[c] = pooled[g * DD + c];
    __syncthreads();
    float t = b1[c];
#pragma unroll 8
    for (int k = 0; k < DD; ++k) t += prow[k] * W1[k * DD + c];
    t = fmaxf(t, 0.f) * W2[c];
#pragma unroll
    for (int m = 32; m >= 1; m >>= 1) t += __shfl_down(t, m);
    if ((c & 63) == 0) wsum[c >> 6] = t;
    __syncthreads();
    if (c == 0) out[g] = wsum[0] + wsum[1] + b2[0];
}

extern "C" void kernel_launch(void* const* d_in, const int* in_sizes, int n_in,
                              void* d_out, int out_size, void* d_ws, size_t ws_size,
                              hipStream_t stream) {
    const float* x    = (const float*)d_in[0];
    const float* pos  = (const float*)d_in[1];
    const int* eidx[4] = {(const int*)d_in[2], (const int*)d_in[3],
                          (const int*)d_in[4], (const int*)d_in[5]};
    const int* batch  = (const int*)d_in[6];
    const float* emb_W  = (const float*)d_in[7];
    const float* emb_b  = (const float*)d_in[8];
    const float* msg_W1 = (const float*)d_in[9];
    const float* msg_b1 = (const float*)d_in[10];
    const float* msg_g1 = (const float*)d_in[11];
    const float* msg_be1= (const float*)d_in[12];
    const float* msg_W2 = (const float*)d_in[13];
    const float* msg_b2 = (const float*)d_in[14];
    const float* msg_g2 = (const float*)d_in[15];
    const float* msg_be2= (const float*)d_in[16];
    const float* upd_W1 = (const float*)d_in[17];
    const float* upd_b1 = (const float*)d_in[18];
    const float* upd_g1 = (const float*)d_in[19];
    const float* upd_be1= (const float*)d_in[20];
    const float* upd_W2 = (const float*)d_in[21];
    const float* upd_b2 = (const float*)d_in[22];
    const float* upd_g2 = (const float*)d_in[23];
    const float* upd_be2= (const float*)d_in[24];
    const float* pred_W1= (const float*)d_in[25];
    const float* pred_b1= (const float*)d_in[26];
    const float* pred_W2= (const float*)d_in[27];
    const float* pred_b2= (const float*)d_in[28];
    float* out = (float*)d_out;

    // ---- workspace layout ----
    float* h      = (float*)d_ws;                    // NN*DD f32
    float* agg    = h + (size_t)NN * DD;             // NN*DD f32
    float* pooled = agg + (size_t)NN * DD;           // NG*DD f32
    int* cnt      = (int*)(pooled + NG * DD);        // 4*NN
    int* rowptr   = cnt + 4 * NN;                    // 4*NN
    int* cursor   = rowptr + 4 * NN;                 // 4*NN
    int* blksum   = cursor + 4 * NN;                 // 4*128
    int* blkoff   = blksum + 4 * 128;                // 4*128
    int* src_s    = blkoff + 4 * 128;                // 4*NE
    int* dst_s    = src_s + 4 * NE;                  // 4*NE
    float* dist_s = (float*)(dst_s + 4 * NE);        // 4*NE
    u16* hb       = (u16*)(dist_s + 4 * NE);         // NN*DD
    u16* Pd0      = hb + (size_t)NN * DD;            // NN*DD
    u16* Ps0      = Pd0 + (size_t)NN * DD;           // NN*DD
    u16* Pd1      = Ps0 + (size_t)NN * DD;           // NN*DD
    u16* Ps1      = Pd1 + (size_t)NN * DD;           // NN*DD
    u16* msgW1T   = Ps1 + (size_t)NN * DD;
    u16* msgW2T   = msgW1T + (size_t)NL * 128 * 256;
    u16* updW1T   = msgW2T + (size_t)NL * 128 * 128;
    u16* updW2T   = updW1T + (size_t)NL * 128 * 256;

    // ---- weight prep (merged) ----
    int wtotal = 2 * (NL * 128 * 256) + 2 * (NL * 128 * 128);
    wprep_all_kernel<<<(wtotal + 255) / 256, 256, 0, stream>>>(
        msg_W1, msg_W2, upd_W1, upd_W2, msgW1T, msgW2T, updW1T, updW2T);

    // ---- CSR build (merged across the 4 sets) ----
    hipMemsetAsync(cnt, 0, 4 * NN * sizeof(int), stream);
    hist_kernel<<<(4 * NE + 255) / 256, 256, 0, stream>>>(
        eidx[0], eidx[1], eidx[2], eidx[3], cnt);
    scanA_kernel<<<4 * NBLK, 256, 0, stream>>>(cnt, rowptr, blksum);
    scanB_kernel<<<4, 128, 0, stream>>>(blksum, blkoff);
    scanC_kernel<<<4 * NBLK, 256, 0, stream>>>(blkoff, rowptr, cursor);
    scatter_kernel<<<(4 * NE + 255) / 256, 256, 0, stream>>>(
        eidx[0], eidx[1], eidx[2], eidx[3], pos, cursor, src_s, dst_s, dist_s);

    // agg must start zeroed; upd re-zeroes per layer
    hipMemsetAsync(agg, 0, (size_t)NN * DD * sizeof(float), stream);

    embed_kernel<<<(NN * DD + 255) / 256, 256, 0, stream>>>(x, emb_W, emb_b, h, hb);
    pre_kernel<<<dim3(NTILE, 2), 256, 0, stream>>>(hb, msgW1T, msg_b1, Pd0, Ps0);

    u16* PdA[2] = {Pd0, Pd1};
    u16* PsA[2] = {Ps0, Ps1};

    for (int li = 0; li < NL; ++li) {
        int gi = li & 3;
        int cur = li & 1, nxt = cur ^ 1;
        int donext = (li + 1 < NL) ? 1 : 0;
        int lnext = donext ? (li + 1) : li;
        msg_kernel<<<NMSGBLK, 256, 0, stream>>>(
            PdA[cur], PsA[cur],
            src_s + (size_t)gi * NE, dst_s + (size_t)gi * NE, dist_s + (size_t)gi * NE,
            msg_W1 + (size_t)li * 257 * DD + 256 * DD,
            msg_g1 + li * DD, msg_be1 + li * DD,
            msgW2T + (size_t)li * 128 * 128,
            msg_b2 + li * DD, msg_g2 + li * DD, msg_be2 + li * DD,
            agg);
        upd_kernel<<<NTILE, 256, 0, stream>>>(
            h, hb, agg,
            updW1T + (size_t)li * 128 * 256,
            upd_b1 + li * DD, upd_g1 + li * DD, upd_be1 + li * DD,
            updW2T + (size_t)li * 128 * 128,
            upd_b2 + li * DD, upd_g2 + li * DD, upd_be2 + li * DD,
            msgW1T + (size_t)lnext * 128 * 256, msg_b1 + lnext * DD,
            PdA[nxt], PsA[nxt],
            donext);
    }

    hipMemsetAsync(pooled, 0, NG * DD * sizeof(float), stream);
    pool_kernel<<<(NN * DD + 255) / 256, 256, 0, stream>>>(h, batch, pooled);
    pred_kernel<<<NG, 128, 0, stream>>>(pooled, pred_W1, pred_b1, pred_W2, pred_b2, out);
}

// Round 11
// 948.128 us; speedup vs baseline: 1.2296x; 1.2296x over previous
//
#include <hip/hip_runtime.h>
#include <math.h>

#define NN 20000   // nodes
#define NE 100000  // edges per edge set
#define DD 128     // hidden
#define FF 16      // node features
#define NL 12      // layers
#define NG 64      // graphs
#define NBLK 79    // ceil(NN/256)
#define NTILE 313  // ceil(NN/64)

typedef unsigned short u16;
typedef short short8 __attribute__((ext_vector_type(8)));
typedef float f32x4 __attribute__((ext_vector_type(4)));

__device__ __forceinline__ float silu_f(float x) { return x / (1.0f + __expf(-x)); }

__device__ __forceinline__ u16 f2b(float f) {
    union { float f; unsigned int u; } v; v.f = f;
    unsigned int r = v.u + 0x7fffu + ((v.u >> 16) & 1u);
    return (u16)(r >> 16);
}
__device__ __forceinline__ float b2f(u16 b) {
    union { unsigned int u; float f; } v; v.u = ((unsigned int)b) << 16;
    return v.f;
}

// ---- merged weight prep: all 4 tensors, fp32 -> bf16 transposed ----
__device__ __forceinline__ void wprep_one(const float* src, u16* dst, int idx,
                                          int Ksrc, int Kdst) {
    int k = idx % Kdst;
    int c = (idx / Kdst) & 127;
    int l = idx / (Kdst * 128);
    dst[idx] = f2b(src[((size_t)l * Ksrc + k) * 128 + c]);
}
__global__ void wprep_all_kernel(const float* __restrict__ mW1, const float* __restrict__ mW2,
                                 const float* __restrict__ uW1, const float* __restrict__ uW2,
                                 u16* __restrict__ dmW1, u16* __restrict__ dmW2,
                                 u16* __restrict__ duW1, u16* __restrict__ duW2) {
    const int S1 = NL * 128 * 256, S2 = NL * 128 * 128;
    int gid = blockIdx.x * 256 + threadIdx.x;
    if (gid < S1) { wprep_one(mW1, dmW1, gid, 257, 256); return; }
    gid -= S1;
    if (gid < S2) { wprep_one(mW2, dmW2, gid, 128, 128); return; }
    gid -= S2;
    if (gid < S1) { wprep_one(uW1, duW1, gid, 256, 256); return; }
    gid -= S1;
    if (gid < S2) { wprep_one(uW2, duW2, gid, 128, 128); return; }
}

// ---- embedding ----
__global__ void embed_kernel(const float* __restrict__ x, const float* __restrict__ W,
                             const float* __restrict__ b, float* __restrict__ h,
                             u16* __restrict__ hb) {
    int gid = blockIdx.x * 256 + threadIdx.x;
    if (gid >= NN * DD) return;
    int n = gid >> 7, c = gid & 127;
    float s = b[c];
    const float* xr = x + n * FF;
#pragma unroll
    for (int k = 0; k < FF; ++k) s += xr[k] * W[k * DD + c];
    h[gid] = s;
    hb[gid] = f2b(s);
}

// ================== CSR build (once per call, all 4 edge sets) ==================
__global__ void hist_kernel(const int* __restrict__ e0, const int* __restrict__ e1,
                            const int* __restrict__ e2, const int* __restrict__ e3,
                            int* __restrict__ cnt) {
    int g = blockIdx.x * 256 + threadIdx.x;
    if (g >= 4 * NE) return;
    int set = g / NE, e = g - set * NE;
    const int* ei = (set == 0) ? e0 : (set == 1) ? e1 : (set == 2) ? e2 : e3;
    atomicAdd(&cnt[set * NN + ei[NE + e]], 1);
}

__global__ __launch_bounds__(256)
void scanA_kernel(const int* __restrict__ cnt, int* __restrict__ rowptr,
                  int* __restrict__ blksum) {
    int set = blockIdx.x / NBLK, blk = blockIdx.x % NBLK;
    int t = threadIdx.x, idx = blk * 256 + t;
    int v = (idx < NN) ? cnt[set * NN + idx] : 0;
    __shared__ int part[256];
    part[t] = v;
    __syncthreads();
    for (int off = 1; off < 256; off <<= 1) {
        int nv = (t >= off) ? part[t - off] : 0;
        __syncthreads();
        part[t] += nv;
        __syncthreads();
    }
    if (idx < NN) rowptr[set * NN + idx] = part[t] - v;
    if (t == 255) blksum[set * NBLK + blk] = part[255];
}

__global__ __launch_bounds__(128)
void scanB_kernel(const int* __restrict__ blksum, int* __restrict__ blkoff) {
    int set = blockIdx.x, t = threadIdx.x;
    int v = (t < NBLK) ? blksum[set * NBLK + t] : 0;
    __shared__ int part[128];
    part[t] = v;
    __syncthreads();
    for (int off = 1; off < 128; off <<= 1) {
        int nv = (t >= off) ? part[t - off] : 0;
        __syncthreads();
        part[t] += nv;
        __syncthreads();
    }
    if (t < NBLK) blkoff[set * NBLK + t] = part[t] - v;
}

__global__ __launch_bounds__(256)
void scanC_kernel(const int* __restrict__ blkoff, int* __restrict__ rowptr,
                  int* __restrict__ cursor) {
    int set = blockIdx.x / NBLK, blk = blockIdx.x % NBLK;
    int t = threadIdx.x, idx = blk * 256 + t;
    if (idx >= NN) return;
    int r = rowptr[set * NN + idx] + blkoff[set * NBLK + blk];
    rowptr[set * NN + idx] = r;
    cursor[set * NN + idx] = r;
}

__global__ void scatter_kernel(const int* __restrict__ e0, const int* __restrict__ e1,
                               const int* __restrict__ e2, const int* __restrict__ e3,
                               const float* __restrict__ pos,
                               int* __restrict__ cursor,
                               int* __restrict__ src_s, int* __restrict__ dst_s,
                               float* __restrict__ dist_s) {
    int g = blockIdx.x * 256 + threadIdx.x;
    if (g >= 4 * NE) return;
    int set = g / NE, e = g - set * NE;
    const int* ei = (set == 0) ? e0 : (set == 1) ? e1 : (set == 2) ? e2 : e3;
    int s = ei[e], d = ei[NE + e];
    int p = atomicAdd(&cursor[set * NN + d], 1);
    float dx = pos[d * 3 + 0] - pos[s * 3 + 0];
    float dy = pos[d * 3 + 1] - pos[s * 3 + 1];
    float dz = pos[d * 3 + 2] - pos[s * 3 + 2];
    src_s[(size_t)set * NE + p] = s;
    dst_s[(size_t)set * NE + p] = d;
    dist_s[(size_t)set * NE + p] = sqrtf(dx * dx + dy * dy + dz * dz);
}

// ===== initial pre (layer 0 only): Pd = h@W1[0:128]+b1 ; Ps = h@W1[128:256] =====
__global__ __launch_bounds__(256, 4)
void pre_kernel(const u16* __restrict__ hb, const u16* __restrict__ W1T,
                const float* __restrict__ b1,
                u16* __restrict__ Pd, u16* __restrict__ Ps) {
    __shared__ __align__(16) u16 As[64 * 40];
    __shared__ __align__(16) u16 Ws[128 * 40];

    const int tid = threadIdx.x;
    const int lane = tid & 63;
    const int w = tid >> 6;
    const int r0 = w * 16;
    const int arow = lane & 15;
    const int kg = lane >> 4;
    const int n0 = blockIdx.x * 64;
    const int part = blockIdx.y;
    u16* outp = part ? Ps : Pd;

    f32x4 acc[8];
#pragma unroll
    for (int t = 0; t < 8; ++t) acc[t] = (f32x4)0.f;

    const int s_row = tid >> 2, s_k8 = (tid & 3) * 8;
    const int w_col = tid >> 1, w_k16 = (tid & 1) * 16;

    for (int kc = 0; kc < 4; ++kc) {
        const int kb = kc * 32;
        {
            int n = n0 + s_row;
            int nn = (n < NN) ? n : 0;
            *(short8*)&As[s_row * 40 + s_k8] =
                *(const short8*)&hb[(size_t)nn * DD + kb + s_k8];
            const u16* wsrc = &W1T[(size_t)w_col * 256 + part * 128 + kb + w_k16];
            *(short8*)&Ws[w_col * 40 + w_k16]     = *(const short8*)&wsrc[0];
            *(short8*)&Ws[w_col * 40 + w_k16 + 8] = *(const short8*)&wsrc[8];
        }
        __syncthreads();
        short8 a = *(const short8*)&As[(r0 + arow) * 40 + kg * 8];
#pragma unroll
        for (int t = 0; t < 8; ++t) {
            short8 b = *(const short8*)&Ws[(t * 16 + arow) * 40 + kg * 8];
            acc[t] = __builtin_amdgcn_mfma_f32_16x16x32_bf16(a, b, acc[t], 0, 0, 0);
        }
        __syncthreads();
    }

#pragma unroll
    for (int r = 0; r < 4; ++r) {
        int n = n0 + r0 + kg * 4 + r;
        if (n < NN) {
            u16* op = &outp[(size_t)n * DD];
#pragma unroll
            for (int t = 0; t < 8; ++t) {
                int col = t * 16 + arow;
                float v = acc[t][r] + (part == 0 ? b1[col] : 0.f);
                op[col] = f2b(v);
            }
        }
    }
}

// =======================================================================
// msg: edge MLP, phase A in MFMA A-fragment registers; 1 chunk per block,
// full W2 in LDS, 2 barriers total  [R9 optimum: 3 blk/CU, 1563-block grid]
// =======================================================================
__global__ __launch_bounds__(256, 3)
void msg_kernel(const u16* __restrict__ Pd, const u16* __restrict__ Ps,
                const int* __restrict__ src_s, const int* __restrict__ dst_s,
                const float* __restrict__ dist_s,
                const float* __restrict__ wd,
                const float* __restrict__ g1, const float* __restrict__ be1,
                const u16* __restrict__ W2T,
                const float* __restrict__ b2, const float* __restrict__ g2,
                const float* __restrict__ be2,
                float* __restrict__ agg) {
    __shared__ __align__(16) u16 Ws[128 * 136];  // full W2 [c][k], stride-136 pad
    __shared__ __align__(16) u16 Mt[64 * 128];   // LN2 output for segmented reduce
    __shared__ int dlS[64];

    const int tid = threadIdx.x;
    const int lane = tid & 63;
    const int w = tid >> 6;
    const int r0 = w * 16;
    const int arow = lane & 15;
    const int kg = lane >> 4;
    const int e0 = blockIdx.x * 64;

#pragma unroll
    for (int q = 0; q < 8; ++q) {
        int idx = q * 256 + tid;
        int c = idx >> 4, k8 = (idx & 15) * 8;
        *(short8*)&Ws[c * 136 + k8] = *(const short8*)&W2T[(size_t)c * 128 + k8];
    }

    const int erow = r0 + arow;
    const int slot = e0 + erow;
    const bool valid = slot < NE;
    int sn = 0, dn = 0; float dist = 0.f;
    if (valid) { sn = src_s[slot]; dn = dst_s[slot]; dist = dist_s[slot]; }
    if (kg == 0) dlS[erow] = valid ? dn : -1;

    float vals[4][8];
    float s1 = 0.f, s2 = 0.f;
#pragma unroll
    for (int kc = 0; kc < 4; ++kc) {
        int kb = kc * 32 + kg * 8;
        short8 pd = *(const short8*)&Pd[(size_t)dn * DD + kb];
        short8 ps = *(const short8*)&Ps[(size_t)sn * DD + kb];
        float4 w0 = *(const float4*)&wd[kb];
        float4 w1 = *(const float4*)&wd[kb + 4];
        float wv[8] = {w0.x, w0.y, w0.z, w0.w, w1.x, w1.y, w1.z, w1.w};
#pragma unroll
        for (int j = 0; j < 8; ++j) {
            float val = b2f((u16)pd[j]) + b2f((u16)ps[j]) + dist * wv[j];
            vals[kc][j] = val;
            s1 += val; s2 += val * val;
        }
    }
    s1 += __shfl_xor(s1, 16); s2 += __shfl_xor(s2, 16);
    s1 += __shfl_xor(s1, 32); s2 += __shfl_xor(s2, 32);
    float mu = s1 * (1.f / 128.f);
    float var = s2 * (1.f / 128.f) - mu * mu;
    float rs = rsqrtf(var + 1e-5f);

    short8 afrag[4];
#pragma unroll
    for (int kc = 0; kc < 4; ++kc) {
        int kb = kc * 32 + kg * 8;
        float4 ga = *(const float4*)&g1[kb];
        float4 gb = *(const float4*)&g1[kb + 4];
        float4 ea = *(const float4*)&be1[kb];
        float4 eb = *(const float4*)&be1[kb + 4];
        float gv[8] = {ga.x, ga.y, ga.z, ga.w, gb.x, gb.y, gb.z, gb.w};
        float ev[8] = {ea.x, ea.y, ea.z, ea.w, eb.x, eb.y, eb.z, eb.w};
        u16 tmp[8];
#pragma unroll
        for (int j = 0; j < 8; ++j) {
            float val = (vals[kc][j] - mu) * rs * gv[j] + ev[j];
            tmp[j] = f2b(silu_f(val));
        }
        afrag[kc] = *(const short8*)tmp;
    }

    __syncthreads();  // Ws + dlS published

    f32x4 acc[8];
#pragma unroll
    for (int t = 0; t < 8; ++t) acc[t] = (f32x4)0.f;
#pragma unroll
    for (int kc = 0; kc < 4; ++kc) {
#pragma unroll
        for (int t = 0; t < 8; ++t) {
            short8 b = *(const short8*)&Ws[(t * 16 + arow) * 136 + kc * 32 + kg * 8];
            acc[t] = __builtin_amdgcn_mfma_f32_16x16x32_bf16(afrag[kc], b, acc[t], 0, 0, 0);
        }
    }

    {
        float gg[8], ee[8], bb[8];
#pragma unroll
        for (int t = 0; t < 8; ++t) {
            int col = t * 16 + arow;
            bb[t] = b2[col]; gg[t] = g2[col]; ee[t] = be2[col];
        }
#pragma unroll
        for (int r = 0; r < 4; ++r) {
            int row = r0 + kg * 4 + r;
            float t1 = 0.f, t2 = 0.f;
#pragma unroll
            for (int t = 0; t < 8; ++t) {
                float val = acc[t][r] + bb[t]; acc[t][r] = val; t1 += val; t2 += val * val;
            }
#pragma unroll
            for (int m = 1; m < 16; m <<= 1) { t1 += __shfl_xor(t1, m); t2 += __shfl_xor(t2, m); }
            float mu2 = t1 * (1.f / 128.f);
            float var2 = t2 * (1.f / 128.f) - mu2 * mu2;
            float rs2 = rsqrtf(var2 + 1e-5f);
#pragma unroll
            for (int t = 0; t < 8; ++t) {
                float val = (acc[t][r] - mu2) * rs2 * gg[t] + ee[t];
                Mt[row * 128 + t * 16 + arow] = f2b(silu_f(val));
            }
        }
    }
    __syncthreads();

    {
        int col = tid & 127;
        int half = tid >> 7;
        int rb = half * 32;
        int prev_dst = (rb == 0) ? ((e0 > 0) ? dst_s[e0 - 1] : -2) : dlS[31];
        int next_dst = (rb == 0) ? dlS[32]
                                 : ((e0 + 64 < NE) ? dst_s[e0 + 64] : -2);
        float run = 0.f;
        int cur = -1;
        bool cur_shared = false;
        for (int r = rb; r < rb + 32; ++r) {
            int d = dlS[r];
            if (d != cur) {
                if (cur >= 0) {
                    float* ap = &agg[(size_t)cur * 128 + col];
                    if (cur_shared) atomicAdd(ap, run); else *ap = run;
                }
                cur = d; run = 0.f;
                cur_shared = (r == rb) && (prev_dst == d);
            }
            if (d >= 0) run += b2f(Mt[r * 128 + col]);
        }
        if (cur >= 0) {
            bool shared_end = (next_dst == cur);
            float* ap = &agg[(size_t)cur * 128 + col];
            if (cur_shared || shared_end) atomicAdd(ap, run); else *ap = run;
        }
    }
}

// =======================================================================
// upd: node MLP + residual + next-layer Pd/Ps
// A-fragments direct from global; ping-pong Ws (1 barrier/chunk)
// =======================================================================
__global__ __launch_bounds__(256, 4)
void upd_kernel(float* __restrict__ h, u16* __restrict__ hb,
                float* __restrict__ agg,
                const u16* __restrict__ W1T,
                const float* __restrict__ b1, const float* __restrict__ g1,
                const float* __restrict__ be1,
                const u16* __restrict__ W2T,
                const float* __restrict__ b2, const float* __restrict__ g2,
                const float* __restrict__ be2,
                const u16* __restrict__ nW1T, const float* __restrict__ nb1,
                u16* __restrict__ Pd_n, u16* __restrict__ Ps_n,
                int donext) {
    __shared__ __align__(16) u16 Ws[2][128 * 40];
    __shared__ __align__(16) u16 Mt[64 * 136];
    u16* newh = Mt;

    const int tid = threadIdx.x;
    const int lane = tid & 63;
    const int w = tid >> 6;
    const int r0 = w * 16;
    const int arow = lane & 15;
    const int kg = lane >> 4;
    const int n0 = blockIdx.x * 64;

    const int w_col = tid >> 1, w_k16 = (tid & 1) * 16;
    const int myn = n0 + r0 + arow;
    const int nclamp = (myn < NN) ? myn : 0;

    f32x4 acc[8];
#pragma unroll
    for (int t = 0; t < 8; ++t) acc[t] = (f32x4)0.f;

    for (int kc = 0; kc < 8; ++kc) {
        const int kb = kc * 32;
        u16* wbuf = Ws[kc & 1];
        {
            const u16* wsrc = &W1T[(size_t)w_col * 256 + kb + w_k16];
            *(short8*)&wbuf[w_col * 40 + w_k16]     = *(const short8*)&wsrc[0];
            *(short8*)&wbuf[w_col * 40 + w_k16 + 8] = *(const short8*)&wsrc[8];
        }
        short8 a;
        if (kc < 4) {
            a = *(const short8*)&hb[(size_t)nclamp * DD + kb + kg * 8];
        } else {
            const float* ap = &agg[(size_t)nclamp * DD + (kb - DD) + kg * 8];
            float4 f0 = *(const float4*)ap;
            float4 f1 = *(const float4*)(ap + 4);
            u16 tmp[8];
            tmp[0] = f2b(f0.x); tmp[1] = f2b(f0.y); tmp[2] = f2b(f0.z); tmp[3] = f2b(f0.w);
            tmp[4] = f2b(f1.x); tmp[5] = f2b(f1.y); tmp[6] = f2b(f1.z); tmp[7] = f2b(f1.w);
            a = *(const short8*)tmp;
        }
        __syncthreads();
#pragma unroll
        for (int t = 0; t < 8; ++t) {
            short8 b = *(const short8*)&wbuf[(t * 16 + arow) * 40 + kg * 8];
            acc[t] = __builtin_amdgcn_mfma_f32_16x16x32_bf16(a, b, acc[t], 0, 0, 0);
        }
    }

    for (int i = tid; i < 64 * 128; i += 256) {
        int n = n0 + (i >> 7);
        if (n < NN) agg[(size_t)n * DD + (i & 127)] = 0.f;
    }

    {
        float gg[8], ee[8], bb[8];
#pragma unroll
        for (int t = 0; t < 8; ++t) {
            int col = t * 16 + arow;
            bb[t] = b1[col]; gg[t] = g1[col]; ee[t] = be1[col];
        }
#pragma unroll
        for (int r = 0; r < 4; ++r) {
            float s1 = 0.f, s2 = 0.f;
#pragma unroll
            for (int t = 0; t < 8; ++t) {
                float v = acc[t][r] + bb[t]; acc[t][r] = v; s1 += v; s2 += v * v;
            }
#pragma unroll
            for (int m = 1; m < 16; m <<= 1) { s1 += __shfl_xor(s1, m); s2 += __shfl_xor(s2, m); }
            float mu = s1 * (1.f / 128.f);
            float var = s2 * (1.f / 128.f) - mu * mu;
            float rs = rsqrtf(var + 1e-5f);
            int row = r0 + kg * 4 + r;
#pragma unroll
            for (int t = 0; t < 8; ++t) {
                float v = (acc[t][r] - mu) * rs * gg[t] + ee[t];
                Mt[row * 136 + t * 16 + arow] = f2b(silu_f(v));
            }
        }
    }

#pragma unroll
    for (int t = 0; t < 8; ++t) acc[t] = (f32x4)0.f;
    for (int kc = 0; kc < 4; ++kc) {
        const int kb = kc * 32;
        u16* wbuf = Ws[kc & 1];
        {
            const u16* wsrc = &W2T[(size_t)w_col * 128 + kb + w_k16];
            *(short8*)&wbuf[w_col * 40 + w_k16]     = *(const short8*)&wsrc[0];
            *(short8*)&wbuf[w_col * 40 + w_k16 + 8] = *(const short8*)&wsrc[8];
        }
        __syncthreads();
        short8 a = *(const short8*)&Mt[(r0 + arow) * 136 + kb + kg * 8];
#pragma unroll
        for (int t = 0; t < 8; ++t) {
            short8 b = *(const short8*)&wbuf[(t * 16 + arow) * 40 + kg * 8];
            acc[t] = __builtin_amdgcn_mfma_f32_16x16x32_bf16(a, b, acc[t], 0, 0, 0);
        }
    }

    {
        float gg[8], ee[8], bb[8];
#pragma unroll
        for (int t = 0; t < 8; ++t) {
            int col = t * 16 + arow;
            bb[t] = b2[col]; gg[t] = g2[col]; ee[t] = be2[col];
        }
#pragma unroll
        for (int r = 0; r < 4; ++r) {
            int row = r0 + kg * 4 + r;
            float s1 = 0.f, s2 = 0.f;
#pragma unroll
            for (int t = 0; t < 8; ++t) {
                float v = acc[t][r] + bb[t]; acc[t][r] = v; s1 += v; s2 += v * v;
            }
#pragma unroll
            for (int m = 1; m < 16; m <<= 1) { s1 += __shfl_xor(s1, m); s2 += __shfl_xor(s2, m); }
            float mu = s1 * (1.f / 128.f);
            float var = s2 * (1.f / 128.f) - mu * mu;
            float rs = rsqrtf(var + 1e-5f);
            int n = n0 + row;
            if (n < NN) {
                float* hp = &h[(size_t)n * DD];
                u16* hbp = &hb[(size_t)n * DD];
#pragma unroll
                for (int t = 0; t < 8; ++t) {
                    int col = t * 16 + arow;
                    float v = (acc[t][r] - mu) * rs * gg[t] + ee[t];
                    float nh = hp[col] + silu_f(v);
                    hp[col] = nh;
                    u16 nb = f2b(nh);
                    hbp[col] = nb;
                    newh[row * 136 + col] = nb;
                }
            } else {
#pragma unroll
                for (int t = 0; t < 8; ++t) newh[row * 136 + t * 16 + arow] = 0;
            }
        }
    }

    if (donext) {
        for (int part = 0; part < 2; ++part) {
#pragma unroll
            for (int t = 0; t < 8; ++t) acc[t] = (f32x4)0.f;
            for (int kc = 0; kc < 4; ++kc) {
                const int kb = kc * 32;
                u16* wbuf = Ws[kc & 1];
                {
                    const u16* wsrc = &nW1T[(size_t)w_col * 256 + part * 128 + kb + w_k16];
                    *(short8*)&wbuf[w_col * 40 + w_k16]     = *(const short8*)&wsrc[0];
                    *(short8*)&wbuf[w_col * 40 + w_k16 + 8] = *(const short8*)&wsrc[8];
                }
                __syncthreads();
                short8 a = *(const short8*)&newh[(r0 + arow) * 136 + kb + kg * 8];
#pragma unroll
                for (int t = 0; t < 8; ++t) {
                    short8 b = *(const short8*)&wbuf[(t * 16 + arow) * 40 + kg * 8];
                    acc[t] = __builtin_amdgcn_mfma_f32_16x16x32_bf16(a, b, acc[t], 0, 0, 0);
                }
            }
            u16* outp = part ? Ps_n : Pd_n;
#pragma unroll
            for (int r = 0; r < 4; ++r) {
                int row = r0 + kg * 4 + r;
                int n = n0 + row;
                if (n < NN) {
                    u16* op = &outp[(size_t)n * DD];
#pragma unroll
                    for (int t = 0; t < 8; ++t) {
                        int col = t * 16 + arow;
                        float v = acc[t][r] + (part == 0 ? nb1[col] : 0.f);
                        op[col] = f2b(v);
                    }
                }
            }
            if (part == 0) __syncthreads();
        }
    }
}

// ---------------- global add pool ----------------
__global__ void pool_kernel(const float* __restrict__ h, const int* __restrict__ batch,
                            float* __restrict__ pooled) {
    int gid = blockIdx.x * 256 + threadIdx.x;
    if (gid >= NN * DD) return;
    int n = gid >> 7, c = gid & 127;
    atomicAdd(&pooled[batch[n] * DD + c], h[gid]);
}

// ---------------- prediction head ----------------
__global__ __launch_bounds__(128)
void pred_kernel(const float* __restrict__ pooled,
                 const float* __restrict__ W1, const float* __restrict__ b1,
                 const float* __restrict__ W2, const float* __restrict__ b2,
                 float* __restrict__ out) {
    __shared__ float prow[128];
    __shared__ float wsum[2];
    int g = blockIdx.x, c = threadIdx.x;
    prow[c] = pooled[g * DD + c];
    __syncthreads();
    float t = b1[c];
#pragma unroll 8
    for (int k = 0; k < DD; ++k) t += prow[k] * W1[k * DD + c];
    t = fmaxf(t, 0.f) * W2[c];
#pragma unroll
    for (int m = 32; m >= 1; m >>= 1) t += __shfl_down(t, m);
    if ((c & 63) == 0) wsum[c >> 6] = t;
    __syncthreads();
    if (c == 0) out[g] = wsum[0] + wsum[1] + b2[0];
}

extern "C" void kernel_launch(void* const* d_in, const int* in_sizes, int n_in,
                              void* d_out, int out_size, void* d_ws, size_t ws_size,
                              hipStream_t stream) {
    const float* x    = (const float*)d_in[0];
    const float* pos  = (const float*)d_in[1];
    const int* eidx[4] = {(const int*)d_in[2], (const int*)d_in[3],
                          (const int*)d_in[4], (const int*)d_in[5]};
    const int* batch  = (const int*)d_in[6];
    const float* emb_W  = (const float*)d_in[7];
    const float* emb_b  = (const float*)d_in[8];
    const float* msg_W1 = (const float*)d_in[9];
    const float* msg_b1 = (const float*)d_in[10];
    const float* msg_g1 = (const float*)d_in[11];
    const float* msg_be1= (const float*)d_in[12];
    const float* msg_W2 = (const float*)d_in[13];
    const float* msg_b2 = (const float*)d_in[14];
    const float* msg_g2 = (const float*)d_in[15];
    const float* msg_be2= (const float*)d_in[16];
    const float* upd_W1 = (const float*)d_in[17];
    const float* upd_b1 = (const float*)d_in[18];
    const float* upd_g1 = (const float*)d_in[19];
    const float* upd_be1= (const float*)d_in[20];
    const float* upd_W2 = (const float*)d_in[21];
    const float* upd_b2 = (const float*)d_in[22];
    const float* upd_g2 = (const float*)d_in[23];
    const float* upd_be2= (const float*)d_in[24];
    const float* pred_W1= (const float*)d_in[25];
    const float* pred_b1= (const float*)d_in[26];
    const float* pred_W2= (const float*)d_in[27];
    const float* pred_b2= (const float*)d_in[28];
    float* out = (float*)d_out;

    // ---- workspace layout ----
    float* h      = (float*)d_ws;                    // NN*DD f32
    float* agg    = h + (size_t)NN * DD;             // NN*DD f32
    float* pooled = agg + (size_t)NN * DD;           // NG*DD f32
    int* cnt      = (int*)(pooled + NG * DD);        // 4*NN
    int* rowptr   = cnt + 4 * NN;                    // 4*NN
    int* cursor   = rowptr + 4 * NN;                 // 4*NN
    int* blksum   = cursor + 4 * NN;                 // 4*128
    int* blkoff   = blksum + 4 * 128;                // 4*128
    int* src_s    = blkoff + 4 * 128;                // 4*NE
    int* dst_s    = src_s + 4 * NE;                  // 4*NE
    float* dist_s = (float*)(dst_s + 4 * NE);        // 4*NE
    u16* hb       = (u16*)(dist_s + 4 * NE);         // NN*DD
    u16* Pd0      = hb + (size_t)NN * DD;            // NN*DD
    u16* Ps0      = Pd0 + (size_t)NN * DD;           // NN*DD
    u16* Pd1      = Ps0 + (size_t)NN * DD;           // NN*DD
    u16* Ps1      = Pd1 + (size_t)NN * DD;           // NN*DD
    u16* msgW1T   = Ps1 + (size_t)NN * DD;
    u16* msgW2T   = msgW1T + (size_t)NL * 128 * 256;
    u16* updW1T   = msgW2T + (size_t)NL * 128 * 128;
    u16* updW2T   = updW1T + (size_t)NL * 128 * 256;

    // ---- weight prep (merged) ----
    int wtotal = 2 * (NL * 128 * 256) + 2 * (NL * 128 * 128);
    wprep_all_kernel<<<(wtotal + 255) / 256, 256, 0, stream>>>(
        msg_W1, msg_W2, upd_W1, upd_W2, msgW1T, msgW2T, updW1T, updW2T);

    // ---- CSR build (merged across the 4 sets) ----
    hipMemsetAsync(cnt, 0, 4 * NN * sizeof(int), stream);
    hist_kernel<<<(4 * NE + 255) / 256, 256, 0, stream>>>(
        eidx[0], eidx[1], eidx[2], eidx[3], cnt);
    scanA_kernel<<<4 * NBLK, 256, 0, stream>>>(cnt, rowptr, blksum);
    scanB_kernel<<<4, 128, 0, stream>>>(blksum, blkoff);
    scanC_kernel<<<4 * NBLK, 256, 0, stream>>>(blkoff, rowptr, cursor);
    scatter_kernel<<<(4 * NE + 255) / 256, 256, 0, stream>>>(
        eidx[0], eidx[1], eidx[2], eidx[3], pos, cursor, src_s, dst_s, dist_s);

    // agg must start zeroed; upd re-zeroes per layer
    hipMemsetAsync(agg, 0, (size_t)NN * DD * sizeof(float), stream);

    embed_kernel<<<(NN * DD + 255) / 256, 256, 0, stream>>>(x, emb_W, emb_b, h, hb);
    pre_kernel<<<dim3(NTILE, 2), 256, 0, stream>>>(hb, msgW1T, msg_b1, Pd0, Ps0);

    u16* PdA[2] = {Pd0, Pd1};
    u16* PsA[2] = {Ps0, Ps1};

    for (int li = 0; li < NL; ++li) {
        int gi = li & 3;
        int cur = li & 1, nxt = cur ^ 1;
        int donext = (li + 1 < NL) ? 1 : 0;
        int lnext = donext ? (li + 1) : li;
        msg_kernel<<<(NE + 63) / 64, 256, 0, stream>>>(
            PdA[cur], PsA[cur],
            src_s + (size_t)gi * NE, dst_s + (size_t)gi * NE, dist_s + (size_t)gi * NE,
            msg_W1 + (size_t)li * 257 * DD + 256 * DD,
            msg_g1 + li * DD, msg_be1 + li * DD,
            msgW2T + (size_t)li * 128 * 128,
            msg_b2 + li * DD, msg_g2 + li * DD, msg_be2 + li * DD,
            agg);
        upd_kernel<<<NTILE, 256, 0, stream>>>(
            h, hb, agg,
            updW1T + (size_t)li * 128 * 256,
            upd_b1 + li * DD, upd_g1 + li * DD, upd_be1 + li * DD,
            updW2T + (size_t)li * 128 * 128,
            upd_b2 + li * DD, upd_g2 + li * DD, upd_be2 + li * DD,
            msgW1T + (size_t)lnext * 128 * 256, msg_b1 + lnext * DD,
            PdA[nxt], PsA[nxt],
            donext);
    }

    hipMemsetAsync(pooled, 0, NG * DD * sizeof(float), stream);
    pool_kernel<<<(NN * DD + 255) / 256, 256, 0, stream>>>(h, batch, pooled);
    pred_kernel<<<NG, 128, 0, stream>>>(pooled, pred_W1, pred_b1, pred_W2, pred_b2, out);
}